// Round 3
// baseline (433.616 us; speedup 1.0000x reference)
//
#include <hip/hip_runtime.h>
#include <math.h>

// Problem constants (from reference)
#define HH   2560
#define ESZ  2048
#define BB   64
#define TT   32
#define INSZ 128
constexpr float ALPHA_C = 0.2f;   // dt_x / tau_x

typedef unsigned short ushort_t;
typedef __attribute__((ext_vector_type(8))) unsigned short u16x8;  // 8 bf16 = 4 VGPRs
typedef __attribute__((ext_vector_type(4))) float f32x4;           // MFMA acc

__device__ __forceinline__ float retanh_f(float v) { return tanhf(fmaxf(v, 0.f)); }
__device__ __forceinline__ ushort_t f2bf(float f) {   // RNE float->bf16
    unsigned u = __float_as_uint(f);
    return (ushort_t)((u + 0x7fffu + ((u >> 16) & 1u)) >> 16);
}

// Area geometry (kron structure). Rows of area a (E and I) share one sparse col set:
// E-cols of areas [a-1..a+1] (n_e), then I-cols of area a (128), then x-cols (area0).
__device__ __forceinline__ int area_ne(int a)  { return (a == 1 || a == 2) ? 1536 : 1024; }
__device__ __forceinline__ int area_elo(int a) { return (a > 0 ? a - 1 : 0) << 9; }

// scatter one act value into B-fragment slots of every area whose col-space has h
// (plain cached stores — used only by the pack kernel; kernel-end flush publishes)
__device__ __forceinline__ void act_store(ushort_t* actF, int a, int p, int b, ushort_t v) {
    int kc = p >> 5, kk = p & 31;
    int lane = ((kk >> 3) << 4) + (b & 15);
    actF[(((a * 52 + kc) << 2) + (b >> 4)) * 512 + lane * 8 + (kk & 7)] = v;
}
__device__ __forceinline__ void scatter_act(ushort_t* actF, int h, int b, ushort_t v) {
    if (h < ESZ) {
        int ae = h >> 9;
        int alo = ae > 0 ? ae - 1 : 0, ahi = ae < 3 ? ae + 1 : 3;
        for (int a = alo; a <= ahi; a++) act_store(actF, a, h - area_elo(a), b, v);
    } else {
        int ai = (h - ESZ) >> 7;
        act_store(actF, ai, area_ne(ai) + (h - (ESZ + (ai << 7))), b, v);
    }
}

// sc0 sc1 variant: write-through to L3 (agent coherence point), no L2 dirty state.
__device__ __forceinline__ void act_store_sc(ushort_t* actF, int a, int p, int b, unsigned v) {
    int kc = p >> 5, kk = p & 31;
    int lane = ((kk >> 3) << 4) + (b & 15);
    ushort_t* addr = actF + (size_t)((((a * 52 + kc) << 2) + (b >> 4)) * 512 + lane * 8 + (kk & 7));
    asm volatile("global_store_short %0, %1, off sc0 sc1" :: "v"(addr), "v"(v) : "memory");
}
__device__ __forceinline__ void scatter_act_sc(ushort_t* actF, int h, int b, unsigned v) {
    if (h < ESZ) {
        int ae = h >> 9;
        int alo = ae > 0 ? ae - 1 : 0, ahi = ae < 3 ? ae + 1 : 3;
        for (int a = alo; a <= ahi; a++) act_store_sc(actF, a, h - area_elo(a), b, v);
    } else {
        int ai = (h - ESZ) >> 7;
        act_store_sc(actF, ai, area_ne(ai) + (h - (ESZ + (ai << 7))), b, v);
    }
}

template<int N> __device__ __forceinline__ void waitv() {
    asm volatile("s_waitcnt vmcnt(%0)" :: "i"(N) : "memory");
}

// ============ fused pack kernel (one dispatch) ============
// bid [0,2080): WF fragments; [2080,3104): xF fragments; [3104,3744): init state/act/flags
__global__ __launch_bounds__(256) void pack_all(
    const float* __restrict__ Wrec, const float* __restrict__ Win,
    const float* __restrict__ x, const float* __restrict__ state0,
    ushort_t* __restrict__ WF, ushort_t* __restrict__ xF,
    float* __restrict__ stateT, ushort_t* __restrict__ actF,
    unsigned* __restrict__ flags)
{
    const int bid = blockIdx.x;
    if (bid < 2080) {
        // WF[(mt*52+kc)*512 + lane*8 + j]: W row m = mt*16+(lane&15),
        // packed col k = kc*32+(lane>>4)*8+j (masked/signed/diag-zeroed |W|, Win appended)
        int idx = bid * 256 + threadIdx.x;   // < 160*52*64
        int l = idx & 63;
        int t = idx >> 6;                 // mt*52 + kc
        int kc = t % 52, mt = t / 52;
        int area = mt / 40, local = mt - area * 40;
        int ridx = local * 16 + (l & 15);
        int h = (ridx < 512) ? ((area << 9) + ridx) : (ESZ + (area << 7) + (ridx - 512));
        int p0 = kc * 32 + ((l >> 4) << 3);
        int ne = area_ne(area), elo = area_elo(area);
        int nrec = ne + 128;
        int ntot = nrec + (area == 0 ? 128 : 0);
        u16x8 o;
#pragma unroll
        for (int j = 0; j < 8; j++) {
            int p = p0 + j;
            float w = 0.f;
            if (p < ne)        { int c = elo + p;                      w = (c == h) ? 0.f :  fabsf(Wrec[(size_t)h * HH + c]); }
            else if (p < nrec) { int c = ESZ + (area << 7) + (p - ne); w = (c == h) ? 0.f : -fabsf(Wrec[(size_t)h * HH + c]); }
            else if (p < ntot) { w = fabsf(Win[(size_t)h * INSZ + (p - nrec)]); }
            o[j] = f2bf(w);
        }
        *(u16x8*)(WF + ((size_t)t * 512 + l * 8)) = o;
    } else if (bid < 3104) {
        // xF[t*8192 + kc*2048 + nt*512 + lane*8 + j] = bf16 relu(x_t) fragment
        int idx = (bid - 2080) * 256 + threadIdx.x;   // < 32*4*4*512
        int j = idx & 7, l = (idx >> 3) & 63;
        int nt = (idx >> 9) & 3, kc = (idx >> 11) & 3, t = idx >> 13;
        int b = nt * 16 + (l & 15);
        int k = kc * 32 + ((l >> 4) << 3) + j;
        xF[idx] = f2bf(fmaxf(x[((size_t)t * BB + b) * INSZ + k], 0.f));
    } else {
        if (bid == 3104 && threadIdx.x < 192)
            flags[threadIdx.x] = 0u;      // flags[0] = global step counter
        int idx = (bid - 3104) * 256 + threadIdx.x;   // < BB*HH
        int b = idx / HH, h = idx - b * HH;
        float s = state0[idx];
        int r = (h < ESZ) ? ((h >> 9) * 640 + (h & 511))
                          : (((h - ESZ) >> 7) * 640 + 512 + ((h - ESZ) & 127));
        stateT[r * BB + b] = s;
        scatter_act(actF, h, b, f2bf(retanh_f(s)));
    }
}

// ============ persistent all-steps kernel ============
// 160 blocks x 256 thr (grid <= #CUs -> co-resident). W fragments persist in VGPRs;
// state/bias in registers. Cross-step actF exchange goes THROUGH L3 via per-access
// sc0|sc1 (bypass L1+L2) loads/stores -- no buffer_wbl2 / buffer_inv anywhere, so
// WF/xF stay warm in L2 for the whole kernel. Barrier: single monotonic agent-scope
// atomic counter (one L3 line); tid0-only poll with s_sleep backoff (low contention).
#define ISSUE_G(dst, g)                                                      \
    _Pragma("unroll")                                                        \
    for (int i = 0; i < NIT; i++) {                                          \
        if (HASX && i == NIT - 1) {                                          \
            const ushort_t* s_ = xt + (g) * 512;                             \
            asm volatile("global_load_dwordx4 %0, %1, off"                   \
                         : "=v"(dst[i]) : "v"(s_));                          \
        } else {                                                             \
            const ushort_t* s_ = bin + (g) * 512 + (size_t)i * 8192;         \
            asm volatile("global_load_dwordx4 %0, %1, off sc0 sc1"           \
                         : "=v"(dst[i]) : "v"(s_));                          \
        }                                                                    \
    }
#define MFMA_G(src, g)                                                       \
    _Pragma("unroll")                                                        \
    for (int i = 0; i < NIT; i++)                                            \
        asm volatile("v_mfma_f32_16x16x32_bf16 %0, %1, %2, %0"               \
                     : "+v"(acc[g]) : "v"(af[i]), "v"(src[i]));

template<int NIT, bool HASX>
__device__ __forceinline__ void run_steps(
    const ushort_t* __restrict__ WF,
    ushort_t* __restrict__ actA, ushort_t* __restrict__ actB,
    const ushort_t* __restrict__ xF, const float* __restrict__ brec,
    const float* __restrict__ stateT, float* __restrict__ out,
    unsigned* __restrict__ flags, float* part, int mt, int area)
{
    const int tid = threadIdx.x, lane = tid & 63, wv = tid >> 6;
    const int ml = mt - area * 40;

    // --- A fragments: load once (cached), persist in VGPRs for all 32 steps ---
    u16x8 af[NIT];
    {
        const ushort_t* aptr = WF + ((size_t)mt * 52 + wv) * 512 + lane * 8;
#pragma unroll
        for (int i = 0; i < NIT; i++) af[i] = *(const u16x8*)(aptr + (size_t)i * 2048);
    }

    // --- per-thread output geometry + register-resident state ---
    const int mm = tid & 15, nn = tid >> 4;
    const int ridx = ml * 16 + mm;
    const int h = (ridx < 512) ? ((area << 9) + ridx) : (ESZ + (area << 7) + (ridx - 512));
    const int r = area * 640 + ml * 16 + mm;
    const float bh = brec[h];
    float st[4];
#pragma unroll
    for (int nt = 0; nt < 4; nt++) st[nt] = stateT[r * BB + nt * 16 + nn];

    const size_t boff = (((size_t)area * 52 + wv) * 4) * 512 + lane * 8;
    const ushort_t* bApt = actA + boff;
    const ushort_t* bBpt = actB + boff;
    const ushort_t* xw = xF + (size_t)(wv * 4) * 512 + lane * 8;

    for (int t = 0; t < TT; t++) {
        const ushort_t* bin = (t & 1) ? bBpt : bApt;     // buffer written last step
        ushort_t* aout      = (t & 1) ? actA : actB;
        const ushort_t* xt  = xw + (size_t)t * 8192;

        f32x4 acc[4];
#pragma unroll
        for (int g = 0; g < 4; g++) acc[g] = (f32x4){0.f, 0.f, 0.f, 0.f};

        // 2-deep pipelined L3 loads with counted in-order vmcnt (m135 semantics)
        u16x8 bf0[NIT], bf1[NIT], bf2[NIT], bf3[NIT];
        ISSUE_G(bf0, 0)
        ISSUE_G(bf1, 1)
        waitv<NIT>();
        MFMA_G(bf0, 0)
        ISSUE_G(bf2, 2)
        waitv<NIT>();
        MFMA_G(bf1, 1)
        ISSUE_G(bf3, 3)
        waitv<NIT>();
        MFMA_G(bf2, 2)
        waitv<0>();
        MFMA_G(bf3, 3)

        // MFMA -> VALU/DS read hazard gap; operand tie pins acc consumers below the nops
        asm volatile("s_nop 7\n\ts_nop 7"
                     : "+v"(acc[0]), "+v"(acc[1]), "+v"(acc[2]), "+v"(acc[3]));

        // C/D layout: n = lane&15, m = (lane>>4)*4 + i   [m89-verified]
        // part row stride 17 (pad) -> conflict-free scalar stores/reads
#pragma unroll
        for (int g = 0; g < 4; g++)
#pragma unroll
            for (int i = 0; i < 4; i++)
                part[(wv * 4 + g) * 272 + (lane & 15) * 17 + ((lane >> 4) << 2) + i] = acc[g][i];
        __syncthreads();

        float* out_t = out + (size_t)t * BB * HH;
        float oo[4];
#pragma unroll
        for (int nt = 0; nt < 4; nt++) {
            float s = 0.f;
#pragma unroll
            for (int w = 0; w < 4; w++) s += part[(w * 4 + nt) * 272 + nn * 17 + mm];
            float ns = st[nt] * (1.f - ALPHA_C) + ALPHA_C * (s + bh);
            st[nt] = ns;
            float o = retanh_f(ns);
            oo[nt] = o;
            scatter_act_sc(aout, h, nt * 16 + nn, (unsigned)f2bf(o));  // coherence-critical first
        }
#pragma unroll
        for (int nt = 0; nt < 4; nt++)
            out_t[(size_t)(nt * 16 + nn) * HH + h] = oo[nt];           // cached; flushed at end

        if (t < TT - 1) {
            // release: drain this wave's sc1 stores to L3, then block-wide barrier, arrive, poll
            asm volatile("s_waitcnt vmcnt(0)" ::: "memory");
            __syncthreads();
            if (tid == 0) {
                __hip_atomic_fetch_add(flags, 1u, __ATOMIC_RELAXED, __HIP_MEMORY_SCOPE_AGENT);
                const unsigned tgt = 160u * (unsigned)(t + 1);
                int guard = 1 << 17;
                while (__hip_atomic_load(flags, __ATOMIC_RELAXED,
                                         __HIP_MEMORY_SCOPE_AGENT) < tgt && --guard)
                    __builtin_amdgcn_s_sleep(1);
            }
            __syncthreads();
            __builtin_amdgcn_sched_barrier(0);
        }
    }
}

__global__ __launch_bounds__(256, 1) void step_all(
    const ushort_t* __restrict__ WF,
    ushort_t* __restrict__ actA, ushort_t* __restrict__ actB,
    const ushort_t* __restrict__ xF, const float* __restrict__ brec,
    const float* __restrict__ stateT, float* __restrict__ out,
    unsigned* __restrict__ flags)
{
    __shared__ float part[16 * 272];      // [wave*4+g][17-padded 16n x 16m]
    const int mt = blockIdx.x;            // 0..159
    const int area = mt / 40;
    if (area == 0)
        run_steps<10, true >(WF, actA, actB, xF, brec, stateT, out, flags, part, mt, 0);
    else if (area == 3)
        run_steps<9,  false>(WF, actA, actB, xF, brec, stateT, out, flags, part, mt, 3);
    else
        run_steps<13, false>(WF, actA, actB, xF, brec, stateT, out, flags, part, mt, area);
}
#undef ISSUE_G
#undef MFMA_G

// ============ fallback (tiny ws): R6's raw-W streaming path ============
__device__ __forceinline__ void area_params(int area, int& e_lo, int& n_e,
                                            int& i_lo, int& n_rec, int& n_tot) {
    e_lo = (area > 0 ? area - 1 : 0) << 9;
    int e_hi = ((area < 3 ? area + 1 : 3) + 1) << 9;
    n_e = e_hi - e_lo;
    i_lo = ESZ + (area << 7);
    n_rec = n_e + 128;
    n_tot = n_rec + (area == 0 ? INSZ : 0);
}
__device__ __forceinline__ int row_h(int area, int idx) {
    return (idx < 512) ? ((area << 9) + idx) : (ESZ + (area << 7) + (idx - 512));
}
__global__ __launch_bounds__(256) void init_state2(const float* __restrict__ state0,
                                                   float* __restrict__ stateT,
                                                   float* __restrict__ act0) {
    int idx = blockIdx.x * 256 + threadIdx.x;
    int b = idx / HH, h = idx - b * HH;
    float s = state0[idx];
    int r = (h < ESZ) ? ((h >> 9) * 640 + (h & 511))
                      : (((h - ESZ) >> 7) * 640 + 512 + ((h - ESZ) & 127));
    stateT[r * BB + b] = s;
    act0[((h >> 1) << 7) + b * 2 + (h & 1)] = retanh_f(s);
}
__global__ __launch_bounds__(1024, 4) void step_raw(
    const float* __restrict__ W, const float* __restrict__ Win,
    const float* __restrict__ brec, const float* __restrict__ x_t,
    const float* __restrict__ actIn, float* __restrict__ actOut,
    float* __restrict__ stateT, float* __restrict__ out_t)
{
    __shared__ float part[16 * 680];
    const int tid = threadIdx.x, lane = tid & 63, wv = tid >> 6;
    const int area = blockIdx.x >> 6;
    const int rb = (blockIdx.x & 63) * 10;
    int e_lo, n_e, i_lo, n_rec, n_tot;
    area_params(area, e_lo, n_e, i_lo, n_rec, n_tot);
    const int r0 = area * 640 + rb;
    const int C = n_tot >> 4;
    float2 acc[10];
#pragma unroll
    for (int j = 0; j < 10; j++) acc[j] = make_float2(0.f, 0.f);
    for (int c = wv; c < C; c += 16) {
        const int p0 = c << 4;
        float2 av[8];
        int cbase;
        if (p0 < n_rec) {
            cbase = (p0 < n_e) ? (e_lo + p0) : (i_lo + (p0 - n_e));
            const float* ap = actIn + ((cbase >> 1) << 7) + lane * 2;
#pragma unroll
            for (int i = 0; i < 8; i++) av[i] = *(const float2*)(ap + (i << 7));
        } else {
            cbase = -1;
            const int k0 = p0 - n_rec;
            const float4* xp = (const float4*)(x_t + lane * INSZ + k0);
#pragma unroll
            for (int q = 0; q < 4; q++) {
                float4 v = xp[q];
                av[2 * q]     = make_float2(fmaxf(v.x, 0.f), fmaxf(v.y, 0.f));
                av[2 * q + 1] = make_float2(fmaxf(v.z, 0.f), fmaxf(v.w, 0.f));
            }
        }
#pragma unroll
        for (int j = 0; j < 10; j++) {
            const int h = row_h(area, rb + j);
            const float sgn = (cbase >= 0 && p0 >= n_e) ? -1.f : 1.f;
            const float* wr = (cbase >= 0) ? (W + (size_t)h * HH + cbase)
                                           : (Win + (size_t)h * INSZ + (p0 - n_rec));
#pragma unroll
            for (int i = 0; i < 8; i++) {
                acc[j].x = fmaf(sgn * fabsf(wr[2 * i]),     av[i].x, acc[j].x);
                acc[j].y = fmaf(sgn * fabsf(wr[2 * i + 1]), av[i].y, acc[j].y);
            }
        }
    }
#pragma unroll
    for (int j = 0; j < 10; j++)
        part[wv * 680 + j * 68 + lane] = acc[j].x + acc[j].y;
    __syncthreads();
    int j = -1, b = 0;
    if (tid < 512)      { b = tid >> 3;      j = tid & 7; }
    else if (tid < 640) { int u = tid - 512; b = u >> 1;  j = 8 + (u & 1); }
    if (j >= 0) {
        const int h = row_h(area, rb + j);
        float s = 0.f;
#pragma unroll
        for (int w16 = 0; w16 < 16; w16++) s += part[w16 * 680 + j * 68 + b];
        float sgn = (h < ESZ) ? 1.f : -1.f;
        s -= sgn * fabsf(W[(size_t)h * HH + h]) * actIn[((h >> 1) << 7) + b * 2 + (h & 1)];
        const int r = r0 + j;
        float st = stateT[r * BB + b];
        float ns = st * (1.f - ALPHA_C) + ALPHA_C * (s + brec[h]);
        stateT[r * BB + b] = ns;
        float o = retanh_f(ns);
        out_t[(size_t)b * HH + h] = o;
        actOut[((h >> 1) << 7) + b * 2 + (h & 1)] = o;
    }
}

extern "C" void kernel_launch(void* const* d_in, const int* in_sizes, int n_in,
                              void* d_out, int out_size, void* d_ws, size_t ws_size,
                              hipStream_t stream) {
    const float* x      = (const float*)d_in[0];
    const float* W_in   = (const float*)d_in[1];
    const float* W_rec  = (const float*)d_in[2];
    const float* b_rec  = (const float*)d_in[3];
    const float* state0 = (const float*)d_in[4];
    float* out = (float*)d_out;

    const size_t WFn = (size_t)160 * 52 * 512;   // 4,259,840 bf16
    const size_t xFn = (size_t)TT * 8192;        //   262,144 bf16
    const size_t aFn = (size_t)4 * 52 * 4 * 512; //   425,984 bf16
    const size_t need = (WFn + xFn + 2 * aFn) * 2 + (size_t)HH * BB * 4 + 192 * 4;

    if (ws_size >= need) {
        ushort_t* WF   = (ushort_t*)d_ws;
        ushort_t* xF   = WF + WFn;
        ushort_t* actA = xF + xFn;
        ushort_t* actB = actA + aFn;
        float* stateT  = (float*)(actB + aFn);
        unsigned* flags = (unsigned*)(stateT + (size_t)HH * BB);

        pack_all<<<3744, 256, 0, stream>>>(W_rec, W_in, x, state0, WF, xF, stateT, actA, flags);
        step_all<<<160, 256, 0, stream>>>(WF, actA, actB, xF, b_rec, stateT, out, flags);
    } else {
        float* ws = (float*)d_ws;
        const size_t bufElems = (size_t)HH * BB;
        float* stateT = ws;
        float* actA   = stateT + bufElems;
        float* actB   = actA + bufElems;
        init_state2<<<(BB * HH) / 256, 256, 0, stream>>>(state0, stateT, actA);
        for (int t = 0; t < TT; t++) {
            const float* ai = (t & 1) ? actB : actA;
            float* ao       = (t & 1) ? actA : actB;
            step_raw<<<256, 1024, 0, stream>>>(W_rec, W_in, b_rec,
                                               x + (size_t)t * BB * INSZ,
                                               ai, ao, stateT, out + (size_t)t * BB * HH);
        }
    }
}

// Round 7
// 276.666 us; speedup vs baseline: 1.5673x; 1.5673x over previous
//
#include <hip/hip_runtime.h>
#include <math.h>

// Problem constants (from reference)
#define HH   2560
#define ESZ  2048
#define BB   64
#define TT   32
#define INSZ 128
constexpr float ALPHA_C = 0.2f;   // dt_x / tau_x

typedef unsigned short ushort_t;
typedef __attribute__((ext_vector_type(8))) unsigned short u16x8;  // 8 bf16 = 4 VGPRs
typedef __attribute__((ext_vector_type(4))) float f32x4;           // MFMA acc

__device__ __forceinline__ float retanh_f(float v) { return tanhf(fmaxf(v, 0.f)); }
__device__ __forceinline__ ushort_t f2bf(float f) {   // RNE float->bf16
    unsigned u = __float_as_uint(f);
    return (ushort_t)((u + 0x7fffu + ((u >> 16) & 1u)) >> 16);
}

// Area geometry (kron structure). Rows of area a (E and I) share one sparse col set:
// E-cols of areas [a-1..a+1] (n_e), then I-cols of area a (128), then x-cols (area0).
__device__ __forceinline__ int area_ne(int a)  { return (a == 1 || a == 2) ? 1536 : 1024; }
__device__ __forceinline__ int area_elo(int a) { return (a > 0 ? a - 1 : 0) << 9; }

// scatter one act value into B-fragment slots of every area whose col-space has h
__device__ __forceinline__ void act_store(ushort_t* actF, int a, int p, int b, ushort_t v) {
    int kc = p >> 5, kk = p & 31;
    int lane = ((kk >> 3) << 4) + (b & 15);
    actF[(((a * 52 + kc) << 2) + (b >> 4)) * 512 + lane * 8 + (kk & 7)] = v;
}
__device__ __forceinline__ void scatter_act(ushort_t* actF, int h, int b, ushort_t v) {
    if (h < ESZ) {
        int ae = h >> 9;
        int alo = ae > 0 ? ae - 1 : 0, ahi = ae < 3 ? ae + 1 : 3;
        for (int a = alo; a <= ahi; a++) act_store(actF, a, h - area_elo(a), b, v);
    } else {
        int ai = (h - ESZ) >> 7;
        act_store(actF, ai, area_ne(ai) + (h - (ESZ + (ai << 7))), b, v);
    }
}

// ============ fused pack kernel (one dispatch) — proven in R2/R3 ============
// bid [0,2080): WF fragments; [2080,3104): xF fragments; [3104,3744): init state/act
__global__ __launch_bounds__(256) void pack_all(
    const float* __restrict__ Wrec, const float* __restrict__ Win,
    const float* __restrict__ x, const float* __restrict__ state0,
    ushort_t* __restrict__ WF, ushort_t* __restrict__ xF,
    float* __restrict__ stateT, ushort_t* __restrict__ actF)
{
    const int bid = blockIdx.x;
    if (bid < 2080) {
        // WF[(mt*52+kc)*512 + lane*8 + j]: W row m = mt*16+(lane&15),
        // packed col k = kc*32+(lane>>4)*8+j (masked/signed/diag-zeroed |W|, Win appended)
        int idx = bid * 256 + threadIdx.x;   // < 160*52*64
        int l = idx & 63;
        int t = idx >> 6;                 // mt*52 + kc
        int kc = t % 52, mt = t / 52;
        int area = mt / 40, local = mt - area * 40;
        int ridx = local * 16 + (l & 15);             // within-area packed row 0..639
        int h = (ridx < 512) ? ((area << 9) + ridx) : (ESZ + (area << 7) + (ridx - 512));
        int p0 = kc * 32 + ((l >> 4) << 3);
        int ne = area_ne(area), elo = area_elo(area);
        int nrec = ne + 128;
        int ntot = nrec + (area == 0 ? 128 : 0);
        u16x8 o;
#pragma unroll
        for (int j = 0; j < 8; j++) {
            int p = p0 + j;
            float w = 0.f;
            if (p < ne)        { int c = elo + p;                      w = (c == h) ? 0.f :  fabsf(Wrec[(size_t)h * HH + c]); }
            else if (p < nrec) { int c = ESZ + (area << 7) + (p - ne); w = (c == h) ? 0.f : -fabsf(Wrec[(size_t)h * HH + c]); }
            else if (p < ntot) { w = fabsf(Win[(size_t)h * INSZ + (p - nrec)]); }
            o[j] = f2bf(w);
        }
        *(u16x8*)(WF + ((size_t)t * 512 + l * 8)) = o;
    } else if (bid < 3104) {
        // xF[t*8192 + kc*2048 + nt*512 + lane*8 + j] = bf16 relu(x_t) fragment
        int idx = (bid - 2080) * 256 + threadIdx.x;   // < 32*4*4*512
        int j = idx & 7, l = (idx >> 3) & 63;
        int nt = (idx >> 9) & 3, kc = (idx >> 11) & 3, t = idx >> 13;
        int b = nt * 16 + (l & 15);
        int k = kc * 32 + ((l >> 4) << 3) + j;
        xF[idx] = f2bf(fmaxf(x[((size_t)t * BB + b) * INSZ + k], 0.f));
    } else {
        // state0 -> stateT (packed-row fp32) + initial act fragments
        int idx = (bid - 3104) * 256 + threadIdx.x;   // < BB*HH
        int b = idx / HH, h = idx - b * HH;
        float s = state0[idx];
        int r = (h < ESZ) ? ((h >> 9) * 640 + (h & 511))
                          : (((h - ESZ) >> 7) * 640 + 512 + ((h - ESZ) & 127));
        stateT[r * BB + b] = s;
        scatter_act(actF, h, b, f2bf(retanh_f(s)));
    }
}

// ============ one RNN step: bf16 MFMA GEMM, fully-unrolled K (R0-verbatim) ============
// 640 blocks x 256 thr (4 waves). Block = (area, mt_local, nt): 16 rows x 16 batch,
// waves K-split 4. Compile-time trip counts per area -> ALL af/bf loads issued
// upfront (<=26 dwordx4 in flight), collapsing 13 serial L2/L3 miss latencies
// (cross-XCD actF) into ~1. bid encode: XCD=bid%8 pins area a to XCD pair {2a,2a+1}.
__global__ __launch_bounds__(256) void step9(
    const ushort_t* __restrict__ WF,
    const ushort_t* __restrict__ actF_in,
    ushort_t* __restrict__ actF_out,
    const ushort_t* __restrict__ xFt,     // this step's x fragments (area0 cols)
    const float* __restrict__ brec,
    float* __restrict__ stateT,           // [r][BB] fp32
    float* __restrict__ out_t)            // [BB][HH] fp32
{
    __shared__ float part[4 * 256];
    const int tid = threadIdx.x, lane = tid & 63, wv = tid >> 6;
    const int bid = blockIdx.x;
    const int area = (bid >> 1) & 3;
    const int nt   = ((bid >> 2) & 2) | (bid & 1);
    const int ml   = bid >> 4;            // mt_local 0..39
    const int mt   = area * 40 + ml;
    const int r0   = area * 640 + ml * 16;

    f32x4 acc = {0.f, 0.f, 0.f, 0.f};
    // kc = wv + 4*i ; af offset = kc*512 ; bf offset = ((area*52+kc)*4+nt)*512
    const ushort_t* aptr = WF + ((size_t)mt * 52 + wv) * 512 + lane * 8;
    const ushort_t* bptr = actF_in + (((size_t)area * 52 + wv) * 4 + nt) * 512 + lane * 8;
    const ushort_t* xptr = xFt + ((wv * 4) + nt) * 512 + lane * 8;   // area0, kc=36+wv

#define KLOOP(NIT, HASX)                                                     \
    {                                                                        \
        u16x8 af[NIT], bf[NIT];                                              \
        _Pragma("unroll")                                                    \
        for (int i = 0; i < (NIT); i++) {                                    \
            af[i] = *(const u16x8*)(aptr + (size_t)i * 2048);                \
            bf[i] = ((HASX) && i == (NIT) - 1)                               \
                        ? *(const u16x8*)xptr                                \
                        : *(const u16x8*)(bptr + (size_t)i * 8192);          \
        }                                                                    \
        _Pragma("unroll")                                                    \
        for (int i = 0; i < (NIT); i++)                                      \
            asm volatile("v_mfma_f32_16x16x32_bf16 %0, %1, %2, %0"           \
                         : "+v"(acc) : "v"(af[i]), "v"(bf[i]));              \
    }

    // KC per area: 40 / 52 / 52 / 36 (all %4==0); per-wave NIT = KC/4.
    // Area0: kc in [36,40) are x-chunks -> each wave's LAST iteration.
    if (area == 0)      KLOOP(10, true)
    else if (area == 3) KLOOP(9,  false)
    else                KLOOP(13, false)
#undef KLOOP

    // hazard gap: VALU read of MFMA result needs a few cycles
    asm volatile("s_nop 7\n\ts_nop 7" : "+v"(acc));

    // C/D layout: n = lane&15, m = (lane>>4)*4 + i   [m89-verified]
#pragma unroll
    for (int i = 0; i < 4; i++)
        part[wv * 256 + (lane & 15) * 16 + ((lane >> 4) << 2) + i] = acc[i];
    __syncthreads();

    {   // 256 outputs (16m x 16n), one per thread; mm fastest -> h-consecutive stores
        const int mm = tid & 15, nn = tid >> 4;
        float s = part[nn * 16 + mm] + part[256 + nn * 16 + mm]
                + part[512 + nn * 16 + mm] + part[768 + nn * 16 + mm];
        const int b = nt * 16 + nn;
        const int ridx = ml * 16 + mm;
        const int h = (ridx < 512) ? ((area << 9) + ridx)
                                   : (ESZ + (area << 7) + (ridx - 512));
        const int r = r0 + mm;
        float st = stateT[r * BB + b];
        float ns = st * (1.f - ALPHA_C) + ALPHA_C * (s + brec[h]);
        stateT[r * BB + b] = ns;
        float o = retanh_f(ns);
        out_t[(size_t)b * HH + h] = o;
        scatter_act(actF_out, h, b, f2bf(o));
    }
}

// ============ fallback (tiny ws): R6's raw-W streaming path ============
__device__ __forceinline__ void area_params(int area, int& e_lo, int& n_e,
                                            int& i_lo, int& n_rec, int& n_tot) {
    e_lo = (area > 0 ? area - 1 : 0) << 9;
    int e_hi = ((area < 3 ? area + 1 : 3) + 1) << 9;
    n_e = e_hi - e_lo;
    i_lo = ESZ + (area << 7);
    n_rec = n_e + 128;
    n_tot = n_rec + (area == 0 ? INSZ : 0);
}
__device__ __forceinline__ int row_h(int area, int idx) {
    return (idx < 512) ? ((area << 9) + idx) : (ESZ + (area << 7) + (idx - 512));
}
__global__ __launch_bounds__(256) void init_state2(const float* __restrict__ state0,
                                                   float* __restrict__ stateT,
                                                   float* __restrict__ act0) {
    int idx = blockIdx.x * 256 + threadIdx.x;
    int b = idx / HH, h = idx - b * HH;
    float s = state0[idx];
    int r = (h < ESZ) ? ((h >> 9) * 640 + (h & 511))
                      : (((h - ESZ) >> 7) * 640 + 512 + ((h - ESZ) & 127));
    stateT[r * BB + b] = s;
    act0[((h >> 1) << 7) + b * 2 + (h & 1)] = retanh_f(s);
}
__global__ __launch_bounds__(1024, 4) void step_raw(
    const float* __restrict__ W, const float* __restrict__ Win,
    const float* __restrict__ brec, const float* __restrict__ x_t,
    const float* __restrict__ actIn, float* __restrict__ actOut,
    float* __restrict__ stateT, float* __restrict__ out_t)
{
    __shared__ float part[16 * 680];
    const int tid = threadIdx.x, lane = tid & 63, wv = tid >> 6;
    const int area = blockIdx.x >> 6;
    const int rb = (blockIdx.x & 63) * 10;
    int e_lo, n_e, i_lo, n_rec, n_tot;
    area_params(area, e_lo, n_e, i_lo, n_rec, n_tot);
    const int r0 = area * 640 + rb;
    const int C = n_tot >> 4;
    float2 acc[10];
#pragma unroll
    for (int j = 0; j < 10; j++) acc[j] = make_float2(0.f, 0.f);
    for (int c = wv; c < C; c += 16) {
        const int p0 = c << 4;
        float2 av[8];
        int cbase;
        if (p0 < n_rec) {
            cbase = (p0 < n_e) ? (e_lo + p0) : (i_lo + (p0 - n_e));
            const float* ap = actIn + ((cbase >> 1) << 7) + lane * 2;
#pragma unroll
            for (int i = 0; i < 8; i++) av[i] = *(const float2*)(ap + (i << 7));
        } else {
            cbase = -1;
            const int k0 = p0 - n_rec;
            const float4* xp = (const float4*)(x_t + lane * INSZ + k0);
#pragma unroll
            for (int q = 0; q < 4; q++) {
                float4 v = xp[q];
                av[2 * q]     = make_float2(fmaxf(v.x, 0.f), fmaxf(v.y, 0.f));
                av[2 * q + 1] = make_float2(fmaxf(v.z, 0.f), fmaxf(v.w, 0.f));
            }
        }
#pragma unroll
        for (int j = 0; j < 10; j++) {
            const int h = row_h(area, rb + j);
            const float sgn = (cbase >= 0 && p0 >= n_e) ? -1.f : 1.f;
            const float* wr = (cbase >= 0) ? (W + (size_t)h * HH + cbase)
                                           : (Win + (size_t)h * INSZ + (p0 - n_rec));
#pragma unroll
            for (int i = 0; i < 8; i++) {
                acc[j].x = fmaf(sgn * fabsf(wr[2 * i]),     av[i].x, acc[j].x);
                acc[j].y = fmaf(sgn * fabsf(wr[2 * i + 1]), av[i].y, acc[j].y);
            }
        }
    }
#pragma unroll
    for (int j = 0; j < 10; j++)
        part[wv * 680 + j * 68 + lane] = acc[j].x + acc[j].y;
    __syncthreads();
    int j = -1, b = 0;
    if (tid < 512)      { b = tid >> 3;      j = tid & 7; }
    else if (tid < 640) { int u = tid - 512; b = u >> 1;  j = 8 + (u & 1); }
    if (j >= 0) {
        const int h = row_h(area, rb + j);
        float s = 0.f;
#pragma unroll
        for (int w16 = 0; w16 < 16; w16++) s += part[w16 * 680 + j * 68 + b];
        float sgn = (h < ESZ) ? 1.f : -1.f;
        s -= sgn * fabsf(W[(size_t)h * HH + h]) * actIn[((h >> 1) << 7) + b * 2 + (h & 1)];
        const int r = r0 + j;
        float st = stateT[r * BB + b];
        float ns = st * (1.f - ALPHA_C) + ALPHA_C * (s + brec[h]);
        stateT[r * BB + b] = ns;
        float o = retanh_f(ns);
        out_t[(size_t)b * HH + h] = o;
        actOut[((h >> 1) << 7) + b * 2 + (h & 1)] = o;
    }
}

extern "C" void kernel_launch(void* const* d_in, const int* in_sizes, int n_in,
                              void* d_out, int out_size, void* d_ws, size_t ws_size,
                              hipStream_t stream) {
    const float* x      = (const float*)d_in[0];
    const float* W_in   = (const float*)d_in[1];
    const float* W_rec  = (const float*)d_in[2];
    const float* b_rec  = (const float*)d_in[3];
    const float* state0 = (const float*)d_in[4];
    float* out = (float*)d_out;

    const size_t WFn = (size_t)160 * 52 * 512;   // 4,259,840 bf16
    const size_t xFn = (size_t)TT * 8192;        //   262,144 bf16
    const size_t aFn = (size_t)4 * 52 * 4 * 512; //   425,984 bf16
    const size_t need = (WFn + xFn + 2 * aFn) * 2 + (size_t)HH * BB * 4;

    if (ws_size >= need) {
        ushort_t* WF   = (ushort_t*)d_ws;
        ushort_t* xF   = WF + WFn;
        ushort_t* actA = xF + xFn;
        ushort_t* actB = actA + aFn;
        float* stateT  = (float*)(actB + aFn);

        pack_all<<<3744, 256, 0, stream>>>(W_rec, W_in, x, state0, WF, xF, stateT, actA);
        for (int t = 0; t < TT; t++) {
            ushort_t* ai = (t & 1) ? actB : actA;
            ushort_t* ao = (t & 1) ? actA : actB;
            step9<<<640, 256, 0, stream>>>(WF, ai, ao, xF + (size_t)t * 8192,
                                           b_rec, stateT, out + (size_t)t * BB * HH);
        }
    } else {
        float* ws = (float*)d_ws;
        const size_t bufElems = (size_t)HH * BB;
        float* stateT = ws;
        float* actA   = stateT + bufElems;
        float* actB   = actA + bufElems;
        init_state2<<<(BB * HH) / 256, 256, 0, stream>>>(state0, stateT, actA);
        for (int t = 0; t < TT; t++) {
            const float* ai = (t & 1) ? actB : actA;
            float* ao       = (t & 1) ? actA : actB;
            step_raw<<<256, 1024, 0, stream>>>(W_rec, W_in, b_rec,
                                               x + (size_t)t * BB * INSZ,
                                               ai, ao, stateT, out + (size_t)t * BB * HH);
        }
    }
}